// Round 1
// baseline (378.242 us; speedup 1.0000x reference)
//
#include <hip/hip_runtime.h>
#include <cstdint>
#include <cstddef>

// LLAConv2d: per-sample 1x1 conv == 32 independent GEMMs
//   out[b,o,p] = sum_i K[b,o,i] * x[b,i,p],  K[b] = sum_e alpha[b,e]*ke[e]
// B=32, Cin=Cout=64, P=160*160=25600, fp32.
// Floors: HBM ~67us (420MB @6.3TB/s), fp32 VALU ~43us (no fp32 MFMA on CDNA4).
// R2 (conv ~110us) was phase-serialized: 1 tile/block, stage->full-drain
// barrier->compute => HBM and VALU alternate (67+43 ~= 110).
// R3: 5 tiles/block, ks staged once, xs double-buffered; counted
// s_waitcnt vmcnt(N) + raw s_barrier keep prefetch loads in flight across
// barriers (T3/T4 pattern). Target: max(HBM,VALU) ~= 70-80us for conv.

#define PIX 25600
#define CIN 64
#define COUT 64
#define BATCH 32
#define NEXP 8
#define TILE_PX 128
#define TILES_PER_B (PIX / TILE_PX) // 200
#define TPB 5                       // tiles per block (pipeline depth)
#define GROUPS (TILES_PER_B / TPB)  // 40 -> grid 32*40 = 1280 blocks

__device__ __forceinline__ void load_lds16(const float* g, float* l) {
  // async global->LDS, 16B/lane; global addr per-lane, LDS dst uniform+lane*16
  __builtin_amdgcn_global_load_lds(
      (__attribute__((address_space(1))) void*)(g),
      (__attribute__((address_space(3))) void*)(l), 16, 0, 0);
}

// ---------------- Kernel A: mix kernels, store TRANSPOSED kt[b][i][o] -------
__global__ __launch_bounds__(256) void mix_kernel(
    const float* __restrict__ alpha, const float* __restrict__ ke,
    float* __restrict__ kt) {
  const int b = blockIdx.x >> 3;
  const int seg = blockIdx.x & 7;
  __shared__ float a[NEXP];
  if (threadIdx.x < NEXP) a[threadIdx.x] = alpha[b * NEXP + threadIdx.x];
  __syncthreads();
#pragma unroll
  for (int t = 0; t < 2; t++) {
    const int idx = seg * 512 + t * 256 + threadIdx.x; // idx = o*64 + i
    float s = 0.f;
#pragma unroll
    for (int e = 0; e < NEXP; e++) s += a[e] * ke[e * 4096 + idx];
    const int o = idx >> 6, i = idx & 63;
    kt[b * 4096 + i * 64 + o] = s; // transposed: [i][o]
  }
}

// ---------------- Kernel B: pipelined multi-tile 1x1-conv GEMM --------------
// Block = (sample b) x (5-tile group); 256 threads; 1280 blocks.
// LDS: ks[64][64] (16KB, staged once) + xs[2][64][128] (64KB dbuf) = 80KB
//   -> 2 blocks/CU (8 waves/CU).
// Per-wave vmcnt ledger (global_load_lds + stores share vmcnt, FIFO):
//   prologue: ks(4) + x_tile0(8)
//   iter t:   stage next(8) [if any]; older stores S_{t-1}(8) [if t>0]
//   => wait vmcnt(8) at t==0 (only next-stage outstanding),
//      vmcnt(16) mid-loop (8 stores + 8 next-stage), vmcnt(8) last (stores).
// Raw s_barrier (no vmcnt drain) top: staged data visible to all waves;
// bottom barrier (top of next iter): all waves done reading buf before the
// next stage overwrites it. Compute tile t overlaps HBM fetch of tile t+1.
__global__ __launch_bounds__(256, 2) void conv_kernel(
    const float* __restrict__ x, const float* __restrict__ kt,
    float* __restrict__ out) {
  __shared__ float ks[CIN * COUT];
  __shared__ float xs[2][CIN * TILE_PX];

  const int bid = blockIdx.x;
  const int b = bid / GROUPS;
  const int g = bid - b * GROUPS;
  const int tile0 = g * TPB;

  const int tid = threadIdx.x;
  const int wave = tid >> 6;
  const int lane = tid & 63;
  const int tc = tid >> 5; // 0..7 (channel group of 8)
  const int tp = tid & 31; // 0..31 (pixel group of 4)

  const float* xb = x + (size_t)b * CIN * PIX;
  const float* kb = kt + b * 4096;

  // Stage ks once: 16KB = 16 wave-instrs; wave w does 4 (each 4 K-rows)
#pragma unroll
  for (int j = 0; j < 4; j++) {
    const int r = wave * 4 + j;
    load_lds16(kb + r * 256 + lane * 4, &ks[r * 256]);
  }

  // Stage tile0 into xs[0]: 64 rows x 128 px; wave w rows 16w..16w+15,
  // 2 rows/instr (lanes 0-31 -> row r, 32-63 -> r+1; 512B contiguous/row).
  {
    const float* gs = xb + (size_t)tile0 * TILE_PX;
#pragma unroll
    for (int j = 0; j < 8; j++) {
      const int r = wave * 16 + j * 2;
      load_lds16(gs + (size_t)(r + (lane >> 5)) * PIX + (lane & 31) * 4,
                 &xs[0][r * TILE_PX]);
    }
  }

  for (int t = 0; t < TPB; ++t) {
    const int cur = t & 1;

    if (t) {
      // all waves done reading xs[cur] (ds_reads consumed by FMAs) before
      // anyone overwrites it with the next stage
      __builtin_amdgcn_s_barrier();
      asm volatile("" ::: "memory");
    }

    if (t + 1 < TPB) {
      const float* gs = xb + (size_t)(tile0 + t + 1) * TILE_PX;
      float* dst = xs[cur ^ 1];
#pragma unroll
      for (int j = 0; j < 8; j++) {
        const int r = wave * 16 + j * 2;
        load_lds16(gs + (size_t)(r + (lane >> 5)) * PIX + (lane & 31) * 4,
                   dst + r * TILE_PX);
      }
    }

    // counted wait: current tile's loads (older) complete; next tile's loads
    // and previous tile's stores stay in flight
    if (t == 0 || t + 1 == TPB) {
      asm volatile("s_waitcnt vmcnt(8)" ::: "memory");
    } else {
      asm volatile("s_waitcnt vmcnt(16)" ::: "memory");
    }
    __builtin_amdgcn_s_barrier(); // raw: no vmcnt drain

    float acc[8][4];
#pragma unroll
    for (int c = 0; c < 8; c++)
#pragma unroll
      for (int p = 0; p < 4; p++) acc[c][p] = 0.f;

    // xs read: lane tp reads 16B granule tp of a 512B row -> 32 consecutive
    // granules/wave, conflict-free. ks: 2 distinct addrs/wave -> broadcast.
    const float* xp4 = &xs[cur][tp * 4];
    const float* kp = ks + tc * 8;
#pragma unroll 8
    for (int ii = 0; ii < CIN; ii++) {
      const float4 xv = *(const float4*)(xp4 + ii * TILE_PX);
      const float4 k0 = *(const float4*)(kp + ii * 64);
      const float4 k1 = *(const float4*)(kp + ii * 64 + 4);
      const float kc[8] = {k0.x, k0.y, k0.z, k0.w, k1.x, k1.y, k1.z, k1.w};
      const float xv4[4] = {xv.x, xv.y, xv.z, xv.w};
#pragma unroll
      for (int c = 0; c < 8; c++)
#pragma unroll
        for (int p = 0; p < 4; p++) acc[c][p] = fmaf(kc[c], xv4[p], acc[c][p]);
    }

    // Epilogue: 8 x float4 stores; lanes sharing tc cover 512B contiguous.
    float* ob = out + ((size_t)(b * COUT + tc * 8)) * PIX +
                (size_t)(tile0 + t) * TILE_PX + tp * 4;
#pragma unroll
    for (int c = 0; c < 8; c++) {
      *(float4*)(ob + (size_t)c * PIX) =
          make_float4(acc[c][0], acc[c][1], acc[c][2], acc[c][3]);
    }
  }
}

extern "C" void kernel_launch(void* const* d_in, const int* in_sizes, int n_in,
                              void* d_out, int out_size, void* d_ws,
                              size_t ws_size, hipStream_t stream) {
  const float* x = (const float*)d_in[0];     // [32,64,160,160]
  const float* alpha = (const float*)d_in[1]; // [32,8]
  const float* ke = (const float*)d_in[2];    // [8,64,64,1,1]
  float* out = (float*)d_out;                 // [32,64,160,160]
  float* kt = (float*)d_ws;                   // 32*4096 floats = 512KB scratch

  mix_kernel<<<BATCH * 8, 256, 0, stream>>>(alpha, ke, kt);
  conv_kernel<<<BATCH * GROUPS, 256, 0, stream>>>(x, kt, out);
}